// Round 9
// baseline (205.053 us; speedup 1.0000x reference)
//
#include <hip/hip_runtime.h>
#include <math.h>

#define L2C 25
#define CH  128
#define NB  8
#define NGRP 3
#define GLB 7
#define GLA 13
#define NG  91
#define GPAD 96
#define KPAD 32
#define HROWS 242

typedef short bf16x8 __attribute__((ext_vector_type(8)));
typedef short short4v __attribute__((ext_vector_type(4)));
typedef int   i32x4  __attribute__((ext_vector_type(4)));
typedef float f32x4  __attribute__((ext_vector_type(4)));
typedef unsigned uint2v __attribute__((ext_vector_type(2)));

union frag_u { i32x4 i; bf16x8 h; };

__device__ inline short f2bf(float f) {
  union { float f; unsigned u; } v; v.f = f;
  unsigned r = (v.u + 0x7FFFu + ((v.u >> 16) & 1u)) >> 16;
  return (short)r;
}
__device__ inline float bf2f(short s) {
  union { unsigned u; float f; } v; v.u = ((unsigned)(unsigned short)s) << 16; return v.f;
}
// plain (non-volatile): pure, reorderable
__device__ inline unsigned cvt_pk_bf16(float lo, float hi) {
  unsigned r; asm("v_cvt_pk_bf16_f32 %0, %1, %2" : "=v"(r) : "v"(lo), "v"(hi)); return r;
}

// ---------------- SH tables (bf16), built on device ----------------
// toT[g][s]: semantic s columns. frT[l][kg]: kg-permuted so the from-grid B-frag is a
// direct register reinterpretation of the to-grid C-frags (validated in R8):
// physical g=(2ks+a)*16+lq*4+b  ->  kg = ks*32 + lq*8 + (a*4+b).
__global__ void build_tables_kernel(short* __restrict__ toT, short* __restrict__ frT) {
  const int g = threadIdx.x;
  if (g >= GPAD) return;
  const double PI = 3.14159265358979323846;
  double Y[L2C];
  double wg = 0.0;
  if (g < NG) {
    const int b = g / GLA;
    const int a = g % GLA;
    double xx = cos(PI * (b + 0.75) / (GLB + 0.5));
    double pp = 1.0;
    for (int it = 0; it < 64; ++it) {
      double p0 = 1.0, p1 = xx;
      for (int j = 2; j <= GLB; ++j) { double p2 = ((2.0*j-1.0)*xx*p1 - (j-1.0)*p0)/j; p0 = p1; p1 = p2; }
      pp = GLB * (xx*p1 - p0) / (xx*xx - 1.0);
      xx -= p1 / pp;
    }
    { double p0 = 1.0, p1 = xx;
      for (int j = 2; j <= GLB; ++j) { double p2 = ((2.0*j-1.0)*xx*p1 - (j-1.0)*p0)/j; p0 = p1; p1 = p2; }
      pp = GLB * (xx*p1 - p0) / (xx*xx - 1.0); }
    const double wb = 2.0 / ((1.0 - xx*xx) * pp * pp);
    const double ct = xx;
    const double sx = sqrt(fmax(0.0, 1.0 - ct*ct));
    double P[5][5];
    P[0][0] = 1.0;
    for (int m = 1; m <= 4; ++m) P[m][m] = -(2.0*m - 1.0) * sx * P[m-1][m-1];
    for (int m = 0; m <= 3; ++m) P[m+1][m] = (2.0*m + 1.0) * ct * P[m][m];
    for (int m = 0; m <= 4; ++m)
      for (int l = m + 2; l <= 4; ++l)
        P[l][m] = ((2.0*l-1.0)*ct*P[l-1][m] - (l+m-1.0)*P[l-2][m]) / (l - m);
    const double fact[9] = {1,1,2,6,24,120,720,5040,40320};
    const double phi = (2.0*PI/GLA) * a;
    for (int l = 0; l <= 4; ++l)
      for (int m = 0; m <= l; ++m) {
        double Nlm = sqrt((2.0*l+1.0)/(4.0*PI) * fact[l-m]/fact[l+m]);
        if (m == 0) Y[l*l + l] = Nlm * P[l][0];
        else {
          double base = sqrt(2.0) * Nlm * P[l][m];
          Y[l*l + l + m] = base * cos((double)m * phi);
          Y[l*l + l - m] = base * sin((double)m * phi);
        }
      }
    wg = wb * (2.0*PI/GLA);
  }
  for (int l = 0; l < KPAD; ++l) {
    float tv = (g < NG && l < L2C) ? (float)Y[l] : 0.f;
    toT[g*KPAD + l] = f2bf(tv);
  }
  {
    const int hi = g >> 4, r = g & 15;
    const int ksv = hi >> 1, pa = hi & 1;
    const int lqv = r >> 2,  pb = r & 3;
    const int u  = pa*4 + pb;
    const int kg = ksv*32 + lqv*8 + u;
    for (int l = 0; l < KPAD; ++l)
      frT[l*GPAD + kg] = (g < NG && l < L2C) ? f2bf((float)(wg * Y[l])) : (short)0;
  }
}

__global__ void convert_w_kernel(const float* __restrict__ w1, const float* __restrict__ w2,
                                 short* __restrict__ wb1, short* __restrict__ wb2) {
  const int i = blockIdx.x * 256 + threadIdx.x;
  if (i < 5*CH*CH) { wb1[i] = f2bf(w1[i]); wb2[i] = f2bf(w2[i]); }
}

// ==== persistent 3-group: LN(reg) -> lin1 -> Gaunt(reg handoff) -> lin2 -> reg-residual epilogue ====
__global__ __launch_bounds__(512, 2) void eqv3_fused8(
    const float* __restrict__ x,
    const float* __restrict__ norm_w, const float* __restrict__ norm_b,
    const short* __restrict__ wb1, const float* __restrict__ b1,
    const float* __restrict__ w_tp,
    const short* __restrict__ wb2, const float* __restrict__ b2,
    const short* __restrict__ toT, const short* __restrict__ frT,
    float* __restrict__ out)
{
  __shared__ __align__(16) short hsh[16][HROWS][8];   // 61,952 B
  __shared__ __align__(16) short hg[NB][4][CH][8];    // 65,536 B (lin1 out; later: lin2 staging)

  const int tid  = threadIdx.x;
  const int w    = tid >> 6;
  const int lane = tid & 63;
  const int l16  = lane & 15;
  const int lq   = lane >> 4;
  const int k    = w*16 + l16;    // this wave's channel column

  constexpr int LDEG[L2C] = {0,1,1,1,2,2,2,2,2,3,3,3,3,3,3,3,4,4,4,4,4,4,4,4,4};
  constexpr int BROW[5]   = {0,16,48,96,160};   // rows = (s-d*d)*8 + node
  constexpr int NT[5]     = {1,2,3,4,5};        // 16-row M-tiles per degree

  // ---- hoisted: zero hg slots 24..31 for this wave's k columns (slot 24 rewritten each group) ----
  {
    const i32x4 z = {0,0,0,0};
    #pragma unroll
    for (int n = 0; n < NB; ++n) *(i32x4*)&hg[n][3][k][0] = z;
  }

  // ---- hoisted loop-invariant per-lane constants ----
  const float b1k = b1[k];
  const float b2k = b2[k];
  float wtp[2][4]; int hrowb[2][4];
  #pragma unroll
  for (int mt = 0; mt < 2; ++mt)
    #pragma unroll
    for (int i = 0; i < 4; ++i) {
      const int l = mt*16 + lq*4 + i;
      if (l < L2C) {
        const int d = LDEG[l];
        wtp[mt][i]   = w_tp[d*CH + k];
        hrowb[mt][i] = BROW[d] + (l - d*d)*NB;
      } else { wtp[mt][i] = 0.f; hrowb[mt][i] = -1; }
    }

  float4 xv[13], xn[13];
  // initial x load (group 0)
  {
    const long n0 = (long)blockIdx.x * NGRP * NB;
    const float4* x4 = (const float4*)(x + (n0 + w)*(long)(L2C*CH));
    #pragma unroll
    for (int it = 0; it < 13; ++it) {
      const int j = it*64 + lane;
      if (j < 800) xv[it] = x4[j];
    }
  }

  for (int grp = 0; grp < NGRP; ++grp) {
    const long n0 = ((long)blockIdx.x * NGRP + grp) * NB;

    // ---- LayerNorm: wave w owns node w; x already in xv regs ----
    {
      float s0 = 0.f, s0q = 0.f, sq = 0.f;
      #pragma unroll
      for (int it = 0; it < 13; ++it) {
        const int j = it*64 + lane;
        if (j < 800) {
          const float t = xv[it].x*xv[it].x + xv[it].y*xv[it].y + xv[it].z*xv[it].z + xv[it].w*xv[it].w;
          if (j < 32) { s0 += xv[it].x + xv[it].y + xv[it].z + xv[it].w; s0q += t; }
          else        sq += t;
        }
      }
      #pragma unroll
      for (int o = 1; o < 64; o <<= 1) {
        s0  += __shfl_xor(s0,  o, 64);
        s0q += __shfl_xor(s0q, o, 64);
        sq  += __shfl_xor(sq,  o, 64);
      }
      const float mean0 = s0 * (1.f/CH);
      const float var   = (sq + s0q - CH*mean0*mean0) * (1.f/(L2C*CH));
      const float rstd  = rsqrtf(var + 1e-5f);
      #pragma unroll
      for (int it = 0; it < 13; ++it) {
        const int j = it*64 + lane;
        if (j < 800) {
          const int s = j >> 5;
          const int d = (int)sqrtf((float)s + 0.5f);  // exact floor-sqrt for s<25
          const int row = 8*(s + d) + w;
          const int c32 = j & 31;
          const int c0  = c32 * 4;
          const float4 nw4 = ((const float4*)norm_w)[d*32 + c32];
          float a0 = xv[it].x, a1 = xv[it].y, a2 = xv[it].z, a3 = xv[it].w;
          if (s == 0) {
            const float4 nb4 = ((const float4*)norm_b)[c32];
            a0 = (a0 - mean0)*rstd*nw4.x + nb4.x;
            a1 = (a1 - mean0)*rstd*nw4.y + nb4.y;
            a2 = (a2 - mean0)*rstd*nw4.z + nb4.z;
            a3 = (a3 - mean0)*rstd*nw4.w + nb4.w;
          } else {
            a0 *= rstd*nw4.x; a1 *= rstd*nw4.y; a2 *= rstd*nw4.z; a3 *= rstd*nw4.w;
          }
          uint2v pk; pk[0] = cvt_pk_bf16(a0, a1); pk[1] = cvt_pk_bf16(a2, a3);
          *(uint2v*)&hsh[c0 >> 3][row][c0 & 7] = pk;
        }
      }
    }
    __syncthreads();   // (1) LN staged

    // ---- linear1 -> hg (wave-private k columns) ----
    {
      #pragma unroll
      for (int d = 0; d < 5; ++d) {
        frag_u B[4];
        #pragma unroll
        for (int ks = 0; ks < 4; ++ks)
          B[ks].i = *(const i32x4*)(wb1 + ((d*CH + k)*CH + ks*32 + lq*8));
        #pragma unroll
        for (int mt = 0; mt < NT[d]; ++mt) {
          f32x4 acc = {0.f, 0.f, 0.f, 0.f};
          #pragma unroll
          for (int ks = 0; ks < 4; ++ks) {
            const bf16x8 a = *(const bf16x8*)&hsh[ks*4 + lq][BROW[d] + mt*16 + l16][0];
            acc = __builtin_amdgcn_mfma_f32_16x16x32_bf16(a, B[ks].h, acc, 0, 0, 0);
          }
          const int sl = 2*mt + (lq >> 1);
          if (sl <= 2*d) {
            const int s = d*d + sl;
            #pragma unroll
            for (int i = 0; i < 4; ++i)
              hg[(lq & 1)*4 + i][s >> 3][k][s & 7] = f2bf(acc[i] + ((s == 0) ? b1k : 0.f));
          }
        }
      }
    }
    // Bh prefetch: wave-private columns (this wave wrote them) -- no barrier needed
    frag_u Bh[NB];
    #pragma unroll
    for (int n = 0; n < NB; ++n)
      Bh[n].i = *(const i32x4*)&hg[n][lq][k][0];
    __syncthreads();   // (2) lin1 hsh-reads complete; Gaunt may overwrite hsh

    // ---- Gaunt: 2 independent node streams; from-grid B = register reinterpretation ----
    {
      frag_u Ato[6];
      #pragma unroll
      for (int gt = 0; gt < 6; ++gt)
        Ato[gt].i = *(const i32x4*)(toT + (gt*16 + l16)*KPAD + lq*8);
      frag_u Afr[2][3];
      #pragma unroll
      for (int mt = 0; mt < 2; ++mt)
        #pragma unroll
        for (int ks = 0; ks < 3; ++ks)
          Afr[mt][ks].i = *(const i32x4*)(frT + (mt*16 + l16)*GPAD + ks*32 + lq*8);

      #pragma unroll
      for (int np = 0; np < 4; ++np) {
        const int nA = np, nB2 = np + 4;
        unsigned pA[6][2], pB[6][2];
        #pragma unroll
        for (int gt = 0; gt < 6; ++gt) {
          f32x4 aA = {0.f,0.f,0.f,0.f}, aB = {0.f,0.f,0.f,0.f};
          aA = __builtin_amdgcn_mfma_f32_16x16x32_bf16(Ato[gt].h, Bh[nA].h,  aA, 0, 0, 0);
          aB = __builtin_amdgcn_mfma_f32_16x16x32_bf16(Ato[gt].h, Bh[nB2].h, aB, 0, 0, 0);
          pA[gt][0] = cvt_pk_bf16(aA[0]*aA[0], aA[1]*aA[1]);
          pA[gt][1] = cvt_pk_bf16(aA[2]*aA[2], aA[3]*aA[3]);
          pB[gt][0] = cvt_pk_bf16(aB[0]*aB[0], aB[1]*aB[1]);
          pB[gt][1] = cvt_pk_bf16(aB[2]*aB[2], aB[3]*aB[3]);
        }
        f32x4 acc2A[2] = {{0.f,0.f,0.f,0.f},{0.f,0.f,0.f,0.f}};
        f32x4 acc2B[2] = {{0.f,0.f,0.f,0.f},{0.f,0.f,0.f,0.f}};
        #pragma unroll
        for (int ks = 0; ks < 3; ++ks) {
          frag_u BgA, BgB;
          BgA.i[0] = (int)pA[2*ks][0];   BgA.i[1] = (int)pA[2*ks][1];
          BgA.i[2] = (int)pA[2*ks+1][0]; BgA.i[3] = (int)pA[2*ks+1][1];
          BgB.i[0] = (int)pB[2*ks][0];   BgB.i[1] = (int)pB[2*ks][1];
          BgB.i[2] = (int)pB[2*ks+1][0]; BgB.i[3] = (int)pB[2*ks+1][1];
          acc2A[0] = __builtin_amdgcn_mfma_f32_16x16x32_bf16(Afr[0][ks].h, BgA.h, acc2A[0], 0, 0, 0);
          acc2A[1] = __builtin_amdgcn_mfma_f32_16x16x32_bf16(Afr[1][ks].h, BgA.h, acc2A[1], 0, 0, 0);
          acc2B[0] = __builtin_amdgcn_mfma_f32_16x16x32_bf16(Afr[0][ks].h, BgB.h, acc2B[0], 0, 0, 0);
          acc2B[1] = __builtin_amdgcn_mfma_f32_16x16x32_bf16(Afr[1][ks].h, BgB.h, acc2B[1], 0, 0, 0);
        }
        #pragma unroll
        for (int mt = 0; mt < 2; ++mt)
          #pragma unroll
          for (int i = 0; i < 4; ++i)
            if (hrowb[mt][i] >= 0) {
              hsh[k >> 3][hrowb[mt][i] + nA][k & 7]  = f2bf(acc2A[mt][i] * wtp[mt][i]);
              hsh[k >> 3][hrowb[mt][i] + nB2][k & 7] = f2bf(acc2B[mt][i] * wtp[mt][i]);
            }
      }
    }

    // ---- prefetch next group's x (hidden under lin2 + staging + epilogue) ----
    if (grp < NGRP - 1) {
      const float4* x4n = (const float4*)(x + (n0 + NB + w)*(long)(L2C*CH));
      #pragma unroll
      for (int it = 0; it < 13; ++it) {
        const int j = it*64 + lane;
        if (j < 800) xn[it] = x4n[j];
      }
    }
    __syncthreads();   // (3) Gaunt output staged; hg free for lin2 staging

    // ---- linear2 + bias(l=0) -> staged bf16 in hg area, layout [n][s][c] ----
    {
      short* stg = &hg[0][0][0][0];   // 25600 shorts used
      #pragma unroll
      for (int d = 0; d < 5; ++d) {
        frag_u B[4];
        #pragma unroll
        for (int ks = 0; ks < 4; ++ks)
          B[ks].i = *(const i32x4*)(wb2 + ((d*CH + k)*CH + ks*32 + lq*8));
        #pragma unroll
        for (int mt = 0; mt < NT[d]; ++mt) {
          f32x4 acc = {0.f, 0.f, 0.f, 0.f};
          #pragma unroll
          for (int ks = 0; ks < 4; ++ks) {
            const bf16x8 a = *(const bf16x8*)&hsh[ks*4 + lq][BROW[d] + mt*16 + l16][0];
            acc = __builtin_amdgcn_mfma_f32_16x16x32_bf16(a, B[ks].h, acc, 0, 0, 0);
          }
          const int sl = 2*mt + (lq >> 1);
          if (sl <= 2*d) {
            const int s = d*d + sl;
            #pragma unroll
            for (int i = 0; i < 4; ++i) {
              const int node = (lq & 1)*4 + i;
              stg[(node*L2C + s)*CH + k] = f2bf(acc[i] + ((s == 0) ? b2k : 0.f));
            }
          }
        }
      }
    }
    __syncthreads();   // (4) staged complete

    // ---- epilogue: wave w writes node w; residual from xv REGISTERS (no x re-read) ----
    {
      const short* stg = &hg[0][0][0][0];
      float4* os = (float4*)(out + (n0 + w)*(long)(L2C*CH));
      #pragma unroll
      for (int it = 0; it < 13; ++it) {
        const int j = it*64 + lane;
        if (j < 800) {
          const short4v sv = *(const short4v*)&stg[w*(L2C*CH) + j*4];
          float4 o;
          o.x = bf2f(sv[0]) + xv[it].x;
          o.y = bf2f(sv[1]) + xv[it].y;
          o.z = bf2f(sv[2]) + xv[it].z;
          o.w = bf2f(sv[3]) + xv[it].w;
          os[j] = o;
        }
      }
    }
    // rotate prefetched x into place; barrier also isolates stg reads from next lin1's hg writes
    if (grp < NGRP - 1) {
      #pragma unroll
      for (int it = 0; it < 13; ++it) xv[it] = xn[it];
    }
    __syncthreads();   // (5) epilogue stg reads complete before next group's writes
  }
}

// ---------------- launch ----------------
extern "C" void kernel_launch(void* const* d_in, const int* in_sizes, int n_in,
                              void* d_out, int out_size, void* d_ws, size_t ws_size,
                              hipStream_t stream) {
  const float* x      = (const float*)d_in[0];
  // d_in[1] = batch (unused)
  const float* norm_w = (const float*)d_in[2];
  const float* norm_b = (const float*)d_in[3];
  const float* w1     = (const float*)d_in[4];
  const float* b1     = (const float*)d_in[5];
  const float* w_tp   = (const float*)d_in[6];
  const float* w2     = (const float*)d_in[7];
  const float* b2     = (const float*)d_in[8];
  float* out = (float*)d_out;

  const int N = in_sizes[0] / (L2C*CH);   // 6000
  const int nblk = N / (NB * NGRP);       // 250

  short* wsS = (short*)d_ws;              // ~670 KB
  short* toT = wsS;                       // [96][32]
  short* frT = toT + GPAD*KPAD;           // [32][96]
  short* wb1 = frT + KPAD*GPAD;           // [5][128][128]
  short* wb2 = wb1 + 5*CH*CH;

  build_tables_kernel<<<1, 128, 0, stream>>>(toT, frT);
  convert_w_kernel<<<(5*CH*CH + 255)/256, 256, 0, stream>>>(w1, w2, wb1, wb2);
  eqv3_fused8<<<nblk, 512, 0, stream>>>(x, norm_w, norm_b, wb1, b1, w_tp, wb2, b2, toT, frT, out);
}

// Round 12
// 141.797 us; speedup vs baseline: 1.4461x; 1.4461x over previous
//
#include <hip/hip_runtime.h>
#include <math.h>

#define L2C 25
#define CH  128
#define NB  4
#define GLB 7
#define GLA 13
#define NG  91
#define GPAD 96
#define KPAD 32
#define HROWS 147      // 144 used rows + 3 pad (R4 layout)

typedef short bf16x8 __attribute__((ext_vector_type(8)));
typedef short short4v __attribute__((ext_vector_type(4)));
typedef int   i32x4  __attribute__((ext_vector_type(4)));
typedef float f32x4  __attribute__((ext_vector_type(4)));

union frag_u { i32x4 i; bf16x8 h; };

__device__ inline short f2bf(float f) {
  union { float f; unsigned u; } v; v.f = f;
  unsigned r = (v.u + 0x7FFFu + ((v.u >> 16) & 1u)) >> 16;
  return (short)r;
}
__device__ inline unsigned cvt_pk_bf16(float lo, float hi) {
  unsigned r; asm("v_cvt_pk_bf16_f32 %0, %1, %2" : "=v"(r) : "v"(lo), "v"(hi)); return r;
}

// ---------------- SH tables (bf16), built on device ----------------
// toT[g][s]: SEMANTIC s columns. frT[l][kg]: kg-permuted so the from-grid B-frag is a
// direct register reinterpretation of the to-grid C-frags (validated R8):
// physical g=(2ks+pa)*16+lq*4+pb  ->  kg = ks*32 + lq*8 + (pa*4+pb).
__global__ void build_tables_kernel(short* __restrict__ toT, short* __restrict__ frT) {
  const int g = threadIdx.x;
  if (g >= GPAD) return;
  const double PI = 3.14159265358979323846;
  double Y[L2C];
  double wg = 0.0;
  if (g < NG) {
    const int b = g / GLA;
    const int a = g % GLA;
    double xx = cos(PI * (b + 0.75) / (GLB + 0.5));
    double pp = 1.0;
    for (int it = 0; it < 64; ++it) {
      double p0 = 1.0, p1 = xx;
      for (int j = 2; j <= GLB; ++j) { double p2 = ((2.0*j-1.0)*xx*p1 - (j-1.0)*p0)/j; p0 = p1; p1 = p2; }
      pp = GLB * (xx*p1 - p0) / (xx*xx - 1.0);
      xx -= p1 / pp;
    }
    { double p0 = 1.0, p1 = xx;
      for (int j = 2; j <= GLB; ++j) { double p2 = ((2.0*j-1.0)*xx*p1 - (j-1.0)*p0)/j; p0 = p1; p1 = p2; }
      pp = GLB * (xx*p1 - p0) / (xx*xx - 1.0); }
    const double wb = 2.0 / ((1.0 - xx*xx) * pp * pp);
    const double ct = xx;
    const double sx = sqrt(fmax(0.0, 1.0 - ct*ct));
    double P[5][5];
    P[0][0] = 1.0;
    for (int m = 1; m <= 4; ++m) P[m][m] = -(2.0*m - 1.0) * sx * P[m-1][m-1];
    for (int m = 0; m <= 3; ++m) P[m+1][m] = (2.0*m + 1.0) * ct * P[m][m];
    for (int m = 0; m <= 4; ++m)
      for (int l = m + 2; l <= 4; ++l)
        P[l][m] = ((2.0*l-1.0)*ct*P[l-1][m] - (l+m-1.0)*P[l-2][m]) / (l - m);
    const double fact[9] = {1,1,2,6,24,120,720,5040,40320};
    const double phi = (2.0*PI/GLA) * a;
    for (int l = 0; l <= 4; ++l)
      for (int m = 0; m <= l; ++m) {
        double Nlm = sqrt((2.0*l+1.0)/(4.0*PI) * fact[l-m]/fact[l+m]);
        if (m == 0) Y[l*l + l] = Nlm * P[l][0];
        else {
          double base = sqrt(2.0) * Nlm * P[l][m];
          Y[l*l + l + m] = base * cos((double)m * phi);
          Y[l*l + l - m] = base * sin((double)m * phi);
        }
      }
    wg = wb * (2.0*PI/GLA);
  }
  for (int l = 0; l < KPAD; ++l) {
    float tv = (g < NG && l < L2C) ? (float)Y[l] : 0.f;
    toT[g*KPAD + l] = f2bf(tv);
  }
  {
    const int hi = g >> 4, r = g & 15;
    const int ksv = hi >> 1, pa = hi & 1;
    const int lqv = r >> 2,  pb = r & 3;
    const int kg = ksv*32 + lqv*8 + pa*4 + pb;
    for (int l = 0; l < KPAD; ++l)
      frT[l*GPAD + kg] = (g < NG && l < L2C) ? f2bf((float)(wg * Y[l])) : (short)0;
  }
}

__global__ void convert_w_kernel(const float* __restrict__ w1, const float* __restrict__ w2,
                                 short* __restrict__ wb1, short* __restrict__ wb2) {
  const int i = blockIdx.x * 256 + threadIdx.x;
  if (i < 5*CH*CH) { wb1[i] = f2bf(w1[i]); wb2[i] = f2bf(w2[i]); }
}

// ===== R4 skeleton verbatim + R8 Gaunt register handoff (single diff) =====
__global__ __launch_bounds__(512, 4) void eqv3_fused4b(
    const float* __restrict__ x,
    const float* __restrict__ norm_w, const float* __restrict__ norm_b,
    const short* __restrict__ wb1, const float* __restrict__ b1,
    const float* __restrict__ w_tp,
    const short* __restrict__ wb2, const float* __restrict__ b2,
    const short* __restrict__ toT, const short* __restrict__ frT,
    float* __restrict__ out)
{
  __shared__ __align__(16) short hsh[16][HROWS][8];   // 37,632 B
  __shared__ __align__(16) short hg[NB][4][CH][8];    // 32,768 B
  __shared__ float red[8][3];

  const int tid  = threadIdx.x;
  const int w    = tid >> 6;
  const int lane = tid & 63;
  const int l16  = lane & 15;
  const int lq   = lane >> 4;
  const long n0  = (long)blockIdx.x * NB;

  constexpr int LDEG[L2C] = {0,1,1,1,2,2,2,2,2,3,3,3,3,3,3,3,4,4,4,4,4,4,4,4,4};
  constexpr int BROW[5]   = {0,16,32,64,96};   // padded degree-block starts (rows = sl*4+node)
  constexpr int NT[5]     = {1,1,2,2,3};       // 16-row M-tiles per degree

  const int nd = w >> 1;    // node this wave helps with (2 waves/node)
  const int hh = w & 1;     // half index within the node
  const int k  = w*16 + l16;  // this wave's output-channel column (linears) == Gaunt channel

  // zero hg slots 28..31 (K-dim hygiene); slots 25..27 zeroed by lin1's else-branch
  *(short4v*)&hg[lq][3][k][4] = (short4v){0,0,0,0};

  // ---- LayerNorm stats: 2 waves per node ----
  {
    const float2* x2 = (const float2*)(x + (n0 + nd) * (L2C*CH));
    float s0 = 0.f, s0q = 0.f, sq = 0.f;
    for (int it = 0; it < 13; ++it) {
      const int j = it*128 + hh*64 + lane;
      if (j < L2C*CH/2) {
        const float2 v = x2[j];
        const float t = v.x*v.x + v.y*v.y;
        if (j < 64) { s0 += v.x + v.y; s0q += t; }
        else        sq += t;
      }
    }
    #pragma unroll
    for (int o = 1; o < 64; o <<= 1) {
      s0  += __shfl_xor(s0,  o, 64);
      s0q += __shfl_xor(s0q, o, 64);
      sq  += __shfl_xor(sq,  o, 64);
    }
    if (lane == 0) { red[w][0] = s0; red[w][1] = s0q; red[w][2] = sq; }
  }
  __syncthreads();

  // ---- normalize + affine -> hsh (each wave writes its node's rows, split by s) ----
  {
    const float mean0 = (red[2*nd][0] + red[2*nd+1][0]) * (1.f/CH);
    const float var   = (red[2*nd][1] + red[2*nd+1][1] + red[2*nd][2] + red[2*nd+1][2]
                         - CH*mean0*mean0) * (1.f/(L2C*CH));
    const float rstd  = rsqrtf(var + 1e-5f);
    const float2* x2 = (const float2*)(x + (n0 + nd) * (L2C*CH));
    const int c0 = 2*lane;
    const int sBeg = hh ? 13 : 0;
    const int sEnd = hh ? 25 : 13;
    for (int s = sBeg; s < sEnd; ++s) {
      const int d   = LDEG[s];
      const int row = BROW[d] + (s - d*d)*NB + nd;
      const float2 v = x2[s*64 + lane];
      float a0 = v.x, a1 = v.y;
      if (s == 0) { a0 -= mean0; a1 -= mean0; }
      a0 *= rstd * norm_w[d*CH + c0];
      a1 *= rstd * norm_w[d*CH + c0 + 1];
      if (s == 0) { a0 += norm_b[c0]; a1 += norm_b[c0+1]; }
      const unsigned pk = (unsigned)(unsigned short)f2bf(a0) | ((unsigned)(unsigned short)f2bf(a1) << 16);
      *(unsigned*)&hsh[c0 >> 3][row][c0 & 7] = pk;
    }
  }
  __syncthreads();   // (1) LN staged

  // ---- linear1 -> hg (wave-private k columns) ----
  {
    const float b1k = b1[k];
    #pragma unroll
    for (int d = 0; d < 5; ++d) {
      frag_u B[4];
      #pragma unroll
      for (int ks = 0; ks < 4; ++ks)
        B[ks].i = *(const i32x4*)(wb1 + ((d*CH + k)*CH + ks*32 + lq*8));
      #pragma unroll
      for (int mt = 0; mt < NT[d]; ++mt) {
        f32x4 acc = {0.f, 0.f, 0.f, 0.f};
        #pragma unroll
        for (int ks = 0; ks < 4; ++ks) {
          const bf16x8 a = *(const bf16x8*)&hsh[ks*4 + lq][BROW[d] + mt*16 + l16][0];
          acc = __builtin_amdgcn_mfma_f32_16x16x32_bf16(a, B[ks].h, acc, 0, 0, 0);
        }
        const int sl = mt*4 + lq;           // C row = sl*4 + node, node = acc index i
        const int s  = d*d + sl;
        if (sl <= 2*d) {
          #pragma unroll
          for (int i = 0; i < 4; ++i)
            hg[i][s >> 3][k][s & 7] = f2bf(acc[i] + ((s == 0) ? b1k : 0.f));
        } else if (d == 4) {                // unclaimed slots s=25..27 -> zero (K-dim hygiene)
          #pragma unroll
          for (int i = 0; i < 4; ++i) hg[i][s >> 3][k][s & 7] = 0;
        }
      }
    }
  }
  __syncthreads();   // (2) all lin1 hsh-reads done before Gaunt overwrites hsh

  // ---- Gaunt: registers; from-grid B = register reinterpretation (R8 handoff) ----
  {
    frag_u Ato[6];
    #pragma unroll
    for (int gt = 0; gt < 6; ++gt)
      Ato[gt].i = *(const i32x4*)(toT + (gt*16 + l16)*KPAD + lq*8);
    frag_u Afr[2][3];
    #pragma unroll
    for (int mt = 0; mt < 2; ++mt)
      #pragma unroll
      for (int ks = 0; ks < 3; ++ks)
        Afr[mt][ks].i = *(const i32x4*)(frT + (mt*16 + l16)*GPAD + ks*32 + lq*8);

    float wtp[2][4]; int hrow[2][4];
    #pragma unroll
    for (int mt = 0; mt < 2; ++mt)
      #pragma unroll
      for (int i = 0; i < 4; ++i) {
        const int l = mt*16 + lq*4 + i;
        if (l < L2C) {
          const int d = LDEG[l];
          wtp[mt][i]  = w_tp[d*CH + k];
          hrow[mt][i] = BROW[d] + (l - d*d)*NB;
        } else { wtp[mt][i] = 0.f; hrow[mt][i] = -1; }
      }

    for (int node = 0; node < NB; ++node) {
      frag_u Bh;
      Bh.i = *(const i32x4*)&hg[node][lq][k][0];

      unsigned p[6][2];
      #pragma unroll
      for (int gt = 0; gt < 6; ++gt) {
        f32x4 acc = {0.f, 0.f, 0.f, 0.f};
        acc = __builtin_amdgcn_mfma_f32_16x16x32_bf16(Ato[gt].h, Bh.h, acc, 0, 0, 0);
        p[gt][0] = cvt_pk_bf16(acc[0]*acc[0], acc[1]*acc[1]);
        p[gt][1] = cvt_pk_bf16(acc[2]*acc[2], acc[3]*acc[3]);
      }

      f32x4 acc2[2] = {{0.f,0.f,0.f,0.f},{0.f,0.f,0.f,0.f}};
      #pragma unroll
      for (int ks = 0; ks < 3; ++ks) {
        frag_u Bg;                                  // R8 register handoff (was: 8 bpermutes)
        Bg.i[0] = (int)p[2*ks][0];
        Bg.i[1] = (int)p[2*ks][1];
        Bg.i[2] = (int)p[2*ks+1][0];
        Bg.i[3] = (int)p[2*ks+1][1];
        acc2[0] = __builtin_amdgcn_mfma_f32_16x16x32_bf16(Afr[0][ks].h, Bg.h, acc2[0], 0, 0, 0);
        acc2[1] = __builtin_amdgcn_mfma_f32_16x16x32_bf16(Afr[1][ks].h, Bg.h, acc2[1], 0, 0, 0);
      }
      #pragma unroll
      for (int mt = 0; mt < 2; ++mt)
        #pragma unroll
        for (int i = 0; i < 4; ++i)
          if (hrow[mt][i] >= 0)
            hsh[k >> 3][hrow[mt][i] + node][k & 7] = f2bf(acc2[mt][i] * wtp[mt][i]);
    }
  }
  __syncthreads();   // (3) Gaunt output staged

  // ---- linear2 + bias(l=0) + residual -> direct out ----
  {
    const float b2k = b2[k];
    #pragma unroll
    for (int d = 0; d < 5; ++d) {
      frag_u B[4];
      #pragma unroll
      for (int ks = 0; ks < 4; ++ks)
        B[ks].i = *(const i32x4*)(wb2 + ((d*CH + k)*CH + ks*32 + lq*8));
      #pragma unroll
      for (int mt = 0; mt < NT[d]; ++mt) {
        f32x4 acc = {0.f, 0.f, 0.f, 0.f};
        #pragma unroll
        for (int ks = 0; ks < 4; ++ks) {
          const bf16x8 a = *(const bf16x8*)&hsh[ks*4 + lq][BROW[d] + mt*16 + l16][0];
          acc = __builtin_amdgcn_mfma_f32_16x16x32_bf16(a, B[ks].h, acc, 0, 0, 0);
        }
        const int sl = mt*4 + lq;
        if (sl <= 2*d) {
          const int s = d*d + sl;
          #pragma unroll
          for (int i = 0; i < 4; ++i) {
            const long base = (n0 + i)*(long)(L2C*CH) + s*CH + k;
            out[base] = acc[i] + ((s == 0) ? b2k : 0.f) + x[base];
          }
        }
      }
    }
  }
}

// ---------------- launch ----------------
extern "C" void kernel_launch(void* const* d_in, const int* in_sizes, int n_in,
                              void* d_out, int out_size, void* d_ws, size_t ws_size,
                              hipStream_t stream) {
  const float* x      = (const float*)d_in[0];
  // d_in[1] = batch (unused)
  const float* norm_w = (const float*)d_in[2];
  const float* norm_b = (const float*)d_in[3];
  const float* w1     = (const float*)d_in[4];
  const float* b1     = (const float*)d_in[5];
  const float* w_tp   = (const float*)d_in[6];
  const float* w2     = (const float*)d_in[7];
  const float* b2     = (const float*)d_in[8];
  float* out = (float*)d_out;

  const int N = in_sizes[0] / (L2C*CH);   // 6000

  short* wsS = (short*)d_ws;              // ~340 KB
  short* toT = wsS;                       // [96][32]
  short* frT = toT + GPAD*KPAD;           // [32][96]
  short* wb1 = frT + KPAD*GPAD;           // [5][128][128]
  short* wb2 = wb1 + 5*CH*CH;

  build_tables_kernel<<<1, 128, 0, stream>>>(toT, frT);
  convert_w_kernel<<<(5*CH*CH + 255)/256, 256, 0, stream>>>(w1, w2, wb1, wb2);
  eqv3_fused4b<<<N/NB, 512, 0, stream>>>(x, norm_w, norm_b, wb1, b1, w_tp, wb2, b2, toT, frT, out);
}

// Round 13
// 114.110 us; speedup vs baseline: 1.7970x; 1.2426x over previous
//
#include <hip/hip_runtime.h>
#include <math.h>

#define L2C 25
#define CH  128
#define NB  8
#define GLB 7
#define GLA 13
#define NG  91
#define GPAD 96
#define KPAD 32
#define HROWS 242

typedef short bf16x8 __attribute__((ext_vector_type(8)));
typedef int   i32x4  __attribute__((ext_vector_type(4)));
typedef float f32x4  __attribute__((ext_vector_type(4)));
typedef unsigned uint2v __attribute__((ext_vector_type(2)));

union frag_u { i32x4 i; bf16x8 h; };

__device__ inline short f2bf(float f) {
  union { float f; unsigned u; } v; v.f = f;
  unsigned r = (v.u + 0x7FFFu + ((v.u >> 16) & 1u)) >> 16;
  return (short)r;
}
__device__ inline unsigned cvt_pk_bf16(float lo, float hi) {
  unsigned r; asm("v_cvt_pk_bf16_f32 %0, %1, %2" : "=v"(r) : "v"(lo), "v"(hi)); return r;
}

// ---------------- SH tables (bf16), built on device (identical to R8) ----------------
__global__ void build_tables_kernel(short* __restrict__ toT, short* __restrict__ frT) {
  const int g = threadIdx.x;
  if (g >= GPAD) return;
  const double PI = 3.14159265358979323846;
  double Y[L2C];
  double wg = 0.0;
  if (g < NG) {
    const int b = g / GLA;
    const int a = g % GLA;
    double xx = cos(PI * (b + 0.75) / (GLB + 0.5));
    double pp = 1.0;
    for (int it = 0; it < 64; ++it) {
      double p0 = 1.0, p1 = xx;
      for (int j = 2; j <= GLB; ++j) { double p2 = ((2.0*j-1.0)*xx*p1 - (j-1.0)*p0)/j; p0 = p1; p1 = p2; }
      pp = GLB * (xx*p1 - p0) / (xx*xx - 1.0);
      xx -= p1 / pp;
    }
    { double p0 = 1.0, p1 = xx;
      for (int j = 2; j <= GLB; ++j) { double p2 = ((2.0*j-1.0)*xx*p1 - (j-1.0)*p0)/j; p0 = p1; p1 = p2; }
      pp = GLB * (xx*p1 - p0) / (xx*xx - 1.0); }
    const double wb = 2.0 / ((1.0 - xx*xx) * pp * pp);
    const double ct = xx;
    const double sx = sqrt(fmax(0.0, 1.0 - ct*ct));
    double P[5][5];
    P[0][0] = 1.0;
    for (int m = 1; m <= 4; ++m) P[m][m] = -(2.0*m - 1.0) * sx * P[m-1][m-1];
    for (int m = 0; m <= 3; ++m) P[m+1][m] = (2.0*m + 1.0) * ct * P[m][m];
    for (int m = 0; m <= 4; ++m)
      for (int l = m + 2; l <= 4; ++l)
        P[l][m] = ((2.0*l-1.0)*ct*P[l-1][m] - (l+m-1.0)*P[l-2][m]) / (l - m);
    const double fact[9] = {1,1,2,6,24,120,720,5040,40320};
    const double phi = (2.0*PI/GLA) * a;
    for (int l = 0; l <= 4; ++l)
      for (int m = 0; m <= l; ++m) {
        double Nlm = sqrt((2.0*l+1.0)/(4.0*PI) * fact[l-m]/fact[l+m]);
        if (m == 0) Y[l*l + l] = Nlm * P[l][0];
        else {
          double base = sqrt(2.0) * Nlm * P[l][m];
          Y[l*l + l + m] = base * cos((double)m * phi);
          Y[l*l + l - m] = base * sin((double)m * phi);
        }
      }
    wg = wb * (2.0*PI/GLA);
  }
  for (int l = 0; l < KPAD; ++l) {
    float tv = (g < NG && l < L2C) ? (float)Y[l] : 0.f;
    toT[g*KPAD + l] = f2bf(tv);
  }
  {
    const int hi = g >> 4, r = g & 15;
    const int ksv = hi >> 1, pa = hi & 1;
    const int lqv = r >> 2,  pb = r & 3;
    const int kg = ksv*32 + lqv*8 + pa*4 + pb;
    for (int l = 0; l < KPAD; ++l)
      frT[l*GPAD + kg] = (g < NG && l < L2C) ? f2bf((float)(wg * Y[l])) : (short)0;
  }
}

__global__ void convert_w_kernel(const float* __restrict__ w1, const float* __restrict__ w2,
                                 short* __restrict__ wb1, short* __restrict__ wb2) {
  const int i = blockIdx.x * 256 + threadIdx.x;
  if (i < 5*CH*CH) { wb1[i] = f2bf(w1[i]); wb2[i] = f2bf(w2[i]); }
}

// ==== NB=8, single aliased 64KB LDS buffer -> 2 blocks/CU; deferred lin1 writes; direct out ====
__global__ __launch_bounds__(512, 4) void eqv3_fused8u(
    const float* __restrict__ x,
    const float* __restrict__ norm_w, const float* __restrict__ norm_b,
    const short* __restrict__ wb1, const float* __restrict__ b1,
    const float* __restrict__ w_tp,
    const short* __restrict__ wb2, const float* __restrict__ b2,
    const short* __restrict__ toT, const short* __restrict__ frT,
    float* __restrict__ out)
{
  __shared__ __align__(16) short u[32768];            // 65,536 B single buffer
  short (*hsh)[HROWS][8] = (short (*)[HROWS][8])u;    // view A: [16][242][8]  (61,952 B)
  short (*hg)[4][CH][8]  = (short (*)[4][CH][8])u;    // view B: [8][4][128][8] (65,536 B)

  const int tid  = threadIdx.x;
  const int w    = tid >> 6;
  const int lane = tid & 63;
  const int l16  = lane & 15;
  const int lq   = lane >> 4;
  const long n0  = (long)blockIdx.x * NB;
  const int k    = w*16 + l16;    // this wave's channel column

  constexpr int LDEG[L2C] = {0,1,1,1,2,2,2,2,2,3,3,3,3,3,3,3,4,4,4,4,4,4,4,4,4};
  constexpr int BROW[5]   = {0,16,48,96,160};   // rows = (s-d*d)*8 + node
  constexpr int NT[5]     = {1,2,3,4,5};        // 16-row M-tiles per degree (15 total)

  // ---- LayerNorm: wave w owns node w; x read ONCE as float4 (proven R8) ----
  {
    const float4* x4 = (const float4*)(x + (n0 + w)*(long)(L2C*CH));
    float4 xv[13];
    float s0 = 0.f, s0q = 0.f, sq = 0.f;
    #pragma unroll
    for (int it = 0; it < 13; ++it) {
      const int j = it*64 + lane;
      if (j < 800) {
        xv[it] = x4[j];
        const float t = xv[it].x*xv[it].x + xv[it].y*xv[it].y + xv[it].z*xv[it].z + xv[it].w*xv[it].w;
        if (j < 32) { s0 += xv[it].x + xv[it].y + xv[it].z + xv[it].w; s0q += t; }
        else        sq += t;
      }
    }
    #pragma unroll
    for (int o = 1; o < 64; o <<= 1) {
      s0  += __shfl_xor(s0,  o, 64);
      s0q += __shfl_xor(s0q, o, 64);
      sq  += __shfl_xor(sq,  o, 64);
    }
    const float mean0 = s0 * (1.f/CH);
    const float var   = (sq + s0q - CH*mean0*mean0) * (1.f/(L2C*CH));
    const float rstd  = rsqrtf(var + 1e-5f);
    #pragma unroll
    for (int it = 0; it < 13; ++it) {
      const int j = it*64 + lane;
      if (j < 800) {
        const int s = j >> 5;
        const int d = (int)sqrtf((float)s + 0.5f);  // exact floor-sqrt for s<25
        const int row = 8*(s + d) + w;              // == BROW[d] + (s-d*d)*8 + w
        const int c32 = j & 31;
        const int c0  = c32 * 4;
        const float4 nw4 = ((const float4*)norm_w)[d*32 + c32];
        float a0 = xv[it].x, a1 = xv[it].y, a2 = xv[it].z, a3 = xv[it].w;
        if (s == 0) {
          const float4 nb4 = ((const float4*)norm_b)[c32];
          a0 = (a0 - mean0)*rstd*nw4.x + nb4.x;
          a1 = (a1 - mean0)*rstd*nw4.y + nb4.y;
          a2 = (a2 - mean0)*rstd*nw4.z + nb4.z;
          a3 = (a3 - mean0)*rstd*nw4.w + nb4.w;
        } else {
          a0 *= rstd*nw4.x; a1 *= rstd*nw4.y; a2 *= rstd*nw4.z; a3 *= rstd*nw4.w;
        }
        uint2v pk; pk[0] = cvt_pk_bf16(a0, a1); pk[1] = cvt_pk_bf16(a2, a3);
        *(uint2v*)&hsh[c0 >> 3][row][c0 & 7] = pk;
      }
    }
  }
  __syncthreads();   // (1) LN staged in buffer (hsh view)

  // ---- linear1: accumulate ALL 15 tiles into packed bf16 pairs (reads only) ----
  unsigned pk1[15][2];
  {
    const float b1k = b1[k];
    int t = 0;
    #pragma unroll
    for (int d = 0; d < 5; ++d) {
      frag_u B[4];
      #pragma unroll
      for (int ks = 0; ks < 4; ++ks)
        B[ks].i = *(const i32x4*)(wb1 + ((d*CH + k)*CH + ks*32 + lq*8));
      #pragma unroll
      for (int mt = 0; mt < NT[d]; ++mt, ++t) {
        f32x4 acc = {0.f, 0.f, 0.f, 0.f};
        #pragma unroll
        for (int ks = 0; ks < 4; ++ks) {
          const bf16x8 a = *(const bf16x8*)&hsh[ks*4 + lq][BROW[d] + mt*16 + l16][0];
          acc = __builtin_amdgcn_mfma_f32_16x16x32_bf16(a, B[ks].h, acc, 0, 0, 0);
        }
        const int sl = 2*mt + (lq >> 1);
        const float bb = ((d == 0) & (sl == 0)) ? b1k : 0.f;
        pk1[t][0] = cvt_pk_bf16(acc[0] + bb, acc[1] + bb);
        pk1[t][1] = cvt_pk_bf16(acc[2] + bb, acc[3] + bb);
      }
    }
  }
  __syncthreads();   // (2) ALL lin1 reads complete; buffer reusable in hg view

  // ---- write lin1 output (hg view, wave-private k columns) ----
  {
    const i32x4 z = {0,0,0,0};
    #pragma unroll
    for (int n = 0; n < NB; ++n) *(i32x4*)&hg[n][3][k][0] = z;   // slots 24..31 hygiene
    int t = 0;
    #pragma unroll
    for (int d = 0; d < 5; ++d)
      #pragma unroll
      for (int mt = 0; mt < NT[d]; ++mt, ++t) {
        const int sl = 2*mt + (lq >> 1);
        if (sl <= 2*d) {
          const int s  = d*d + sl;
          const int nb = (lq & 1)*4;
          hg[nb+0][s >> 3][k][s & 7] = (short)(pk1[t][0] & 0xFFFFu);
          hg[nb+1][s >> 3][k][s & 7] = (short)(pk1[t][0] >> 16);
          hg[nb+2][s >> 3][k][s & 7] = (short)(pk1[t][1] & 0xFFFFu);
          hg[nb+3][s >> 3][k][s & 7] = (short)(pk1[t][1] >> 16);
        }
      }
  }

  // ---- Bh prefetch: own k columns (this wave wrote them; no barrier needed) ----
  frag_u Bh[NB];
  #pragma unroll
  for (int n = 0; n < NB; ++n)
    Bh[n].i = *(const i32x4*)&hg[n][lq][k][0];
  __syncthreads();   // (3) all hg reads done; Gaunt may write buffer in hsh view

  // ---- Gaunt: 2 independent node streams; register from-grid handoff (proven R8) ----
  {
    frag_u Ato[6];
    #pragma unroll
    for (int gt = 0; gt < 6; ++gt)
      Ato[gt].i = *(const i32x4*)(toT + (gt*16 + l16)*KPAD + lq*8);
    frag_u Afr[2][3];
    #pragma unroll
    for (int mt = 0; mt < 2; ++mt)
      #pragma unroll
      for (int ks = 0; ks < 3; ++ks)
        Afr[mt][ks].i = *(const i32x4*)(frT + (mt*16 + l16)*GPAD + ks*32 + lq*8);

    float wtp[2][4]; int hrowb[2][4];
    #pragma unroll
    for (int mt = 0; mt < 2; ++mt)
      #pragma unroll
      for (int i = 0; i < 4; ++i) {
        const int l = mt*16 + lq*4 + i;
        if (l < L2C) {
          const int d = LDEG[l];
          wtp[mt][i]   = w_tp[d*CH + k];
          hrowb[mt][i] = BROW[d] + (l - d*d)*NB;
        } else { wtp[mt][i] = 0.f; hrowb[mt][i] = -1; }
      }

    #pragma unroll
    for (int np = 0; np < 4; ++np) {
      const int nA = np, nB2 = np + 4;
      unsigned pA[6][2], pB[6][2];
      #pragma unroll
      for (int gt = 0; gt < 6; ++gt) {
        f32x4 aA = {0.f,0.f,0.f,0.f}, aB = {0.f,0.f,0.f,0.f};
        aA = __builtin_amdgcn_mfma_f32_16x16x32_bf16(Ato[gt].h, Bh[nA].h,  aA, 0, 0, 0);
        aB = __builtin_amdgcn_mfma_f32_16x16x32_bf16(Ato[gt].h, Bh[nB2].h, aB, 0, 0, 0);
        pA[gt][0] = cvt_pk_bf16(aA[0]*aA[0], aA[1]*aA[1]);
        pA[gt][1] = cvt_pk_bf16(aA[2]*aA[2], aA[3]*aA[3]);
        pB[gt][0] = cvt_pk_bf16(aB[0]*aB[0], aB[1]*aB[1]);
        pB[gt][1] = cvt_pk_bf16(aB[2]*aB[2], aB[3]*aB[3]);
      }
      f32x4 acc2A[2] = {{0.f,0.f,0.f,0.f},{0.f,0.f,0.f,0.f}};
      f32x4 acc2B[2] = {{0.f,0.f,0.f,0.f},{0.f,0.f,0.f,0.f}};
      #pragma unroll
      for (int ks = 0; ks < 3; ++ks) {
        frag_u BgA, BgB;
        BgA.i[0] = (int)pA[2*ks][0];   BgA.i[1] = (int)pA[2*ks][1];
        BgA.i[2] = (int)pA[2*ks+1][0]; BgA.i[3] = (int)pA[2*ks+1][1];
        BgB.i[0] = (int)pB[2*ks][0];   BgB.i[1] = (int)pB[2*ks][1];
        BgB.i[2] = (int)pB[2*ks+1][0]; BgB.i[3] = (int)pB[2*ks+1][1];
        acc2A[0] = __builtin_amdgcn_mfma_f32_16x16x32_bf16(Afr[0][ks].h, BgA.h, acc2A[0], 0, 0, 0);
        acc2A[1] = __builtin_amdgcn_mfma_f32_16x16x32_bf16(Afr[1][ks].h, BgA.h, acc2A[1], 0, 0, 0);
        acc2B[0] = __builtin_amdgcn_mfma_f32_16x16x32_bf16(Afr[0][ks].h, BgB.h, acc2B[0], 0, 0, 0);
        acc2B[1] = __builtin_amdgcn_mfma_f32_16x16x32_bf16(Afr[1][ks].h, BgB.h, acc2B[1], 0, 0, 0);
      }
      #pragma unroll
      for (int mt = 0; mt < 2; ++mt)
        #pragma unroll
        for (int i = 0; i < 4; ++i)
          if (hrowb[mt][i] >= 0) {
            hsh[k >> 3][hrowb[mt][i] + nA][k & 7]  = f2bf(acc2A[mt][i] * wtp[mt][i]);
            hsh[k >> 3][hrowb[mt][i] + nB2][k & 7] = f2bf(acc2B[mt][i] * wtp[mt][i]);
          }
    }
  }
  __syncthreads();   // (4) Gaunt output staged (hsh view)

  // ---- linear2 + bias(l=0) + residual -> direct global store (proven R5/R12) ----
  {
    const float b2k = b2[k];
    #pragma unroll
    for (int d = 0; d < 5; ++d) {
      frag_u B[4];
      #pragma unroll
      for (int ks = 0; ks < 4; ++ks)
        B[ks].i = *(const i32x4*)(wb2 + ((d*CH + k)*CH + ks*32 + lq*8));
      #pragma unroll
      for (int mt = 0; mt < NT[d]; ++mt) {
        f32x4 acc = {0.f, 0.f, 0.f, 0.f};
        #pragma unroll
        for (int ks = 0; ks < 4; ++ks) {
          const bf16x8 a = *(const bf16x8*)&hsh[ks*4 + lq][BROW[d] + mt*16 + l16][0];
          acc = __builtin_amdgcn_mfma_f32_16x16x32_bf16(a, B[ks].h, acc, 0, 0, 0);
        }
        const int sl = 2*mt + (lq >> 1);
        if (sl <= 2*d) {
          const int s = d*d + sl;
          #pragma unroll
          for (int i = 0; i < 4; ++i) {
            const int node = (lq & 1)*4 + i;
            const long base = (n0 + node)*(long)(L2C*CH) + s*CH + k;
            out[base] = acc[i] + ((s == 0) ? b2k : 0.f) + x[base];
          }
        }
      }
    }
  }
}

// ---------------- launch ----------------
extern "C" void kernel_launch(void* const* d_in, const int* in_sizes, int n_in,
                              void* d_out, int out_size, void* d_ws, size_t ws_size,
                              hipStream_t stream) {
  const float* x      = (const float*)d_in[0];
  // d_in[1] = batch (unused)
  const float* norm_w = (const float*)d_in[2];
  const float* norm_b = (const float*)d_in[3];
  const float* w1     = (const float*)d_in[4];
  const float* b1     = (const float*)d_in[5];
  const float* w_tp   = (const float*)d_in[6];
  const float* w2     = (const float*)d_in[7];
  const float* b2     = (const float*)d_in[8];
  float* out = (float*)d_out;

  const int N = in_sizes[0] / (L2C*CH);   // 6000

  short* wsS = (short*)d_ws;              // ~340 KB
  short* toT = wsS;                       // [96][32]
  short* frT = toT + GPAD*KPAD;           // [32][96]
  short* wb1 = frT + KPAD*GPAD;           // [5][128][128]
  short* wb2 = wb1 + 5*CH*CH;

  build_tables_kernel<<<1, 128, 0, stream>>>(toT, frT);
  convert_w_kernel<<<(5*CH*CH + 255)/256, 256, 0, stream>>>(w1, w2, wb1, wb2);
  eqv3_fused8u<<<N/NB, 512, 0, stream>>>(x, norm_w, norm_b, wb1, b1, w_tp, wb2, b2, toT, frT, out);
}